// Round 9
// baseline (373.144 us; speedup 1.0000x reference)
//
#include <hip/hip_runtime.h>
#include <cstdint>
#include <cstddef>

#define N_ 4096
#define C_ 256
#define QD 8   // survivor-queue depth per row (LDS budget: keep block < 64 KB)

typedef _Float16 h8 __attribute__((ext_vector_type(8)));
typedef _Float16 h4 __attribute__((ext_vector_type(4)));
typedef float f4 __attribute__((ext_vector_type(4)));

__device__ __forceinline__ void gl2lds16(const void* g, void* l) {
  __builtin_amdgcn_global_load_lds((const __attribute__((address_space(1))) void*)g,
                                   (__attribute__((address_space(3))) void*)l, 16, 0, 0);
}

// -------------------------------------- sq = sum x^2 ; split x -> f16 hi + lo
__global__ __launch_bounds__(256) void k_prep(const float* __restrict__ x,
                                              float* __restrict__ sq,
                                              _Float16* __restrict__ xh,
                                              _Float16* __restrict__ xl) {
  int wave = threadIdx.x >> 6, lane = threadIdx.x & 63;
  int row = blockIdx.x * 4 + wave;            // 0..16383
  size_t off = (size_t)row * C_ + lane * 4;
  float4 v = *(const float4*)(x + off);
  h4 hi; hi[0] = (_Float16)v.x; hi[1] = (_Float16)v.y;
         hi[2] = (_Float16)v.z; hi[3] = (_Float16)v.w;
  h4 lo; lo[0] = (_Float16)(v.x - (float)hi[0]); lo[1] = (_Float16)(v.y - (float)hi[1]);
         lo[2] = (_Float16)(v.z - (float)hi[2]); lo[3] = (_Float16)(v.w - (float)hi[3]);
  *(h4*)(xh + off) = hi;
  *(h4*)(xl + off) = lo;
  float s = v.x * v.x + v.y * v.y + v.z * v.z + v.w * v.w;
  s += __shfl_xor(s, 32); s += __shfl_xor(s, 16); s += __shfl_xor(s, 8);
  s += __shfl_xor(s, 4);  s += __shfl_xor(s, 2);  s += __shfl_xor(s, 1);
  if (lane == 0) sq[row] = s;
}

// ------------------- split W into f16 hi/lo, transposed to B-frag row layout
__global__ __launch_bounds__(256) void k_wsplit(const float* __restrict__ Wq,
                                                const float* __restrict__ Wk,
                                                const float* __restrict__ Wv,
                                                _Float16* __restrict__ wh,
                                                _Float16* __restrict__ wl) {
  int g = blockIdx.x * 256 + threadIdx.x;     // 0..196607
  int m = g >> 16, e = g & 65535;
  int k = e >> 8, j = e & 255;
  const float* W = (m == 0) ? Wq : ((m == 1) ? Wk : Wv);
  float v = W[k * 256 + j];
  _Float16 hi = (_Float16)v;
  _Float16 lo = (_Float16)(v - (float)hi);
  wh[m * 65536 + j * 256 + k] = hi;
  wl[m * 65536 + j * 256 + k] = lo;
}

// --------------------------- q/k/v projections via split-f16 MFMA (3 passes)
// q written f32; k/v written f16 (halves k_attn gather traffic).
__global__ __launch_bounds__(256, 2) void k_proj(const _Float16* __restrict__ xh,
                                                 const _Float16* __restrict__ xl,
                                                 const _Float16* __restrict__ wh,
                                                 const _Float16* __restrict__ wl,
                                                 const float* __restrict__ bqp,
                                                 const float* __restrict__ bkp,
                                                 const float* __restrict__ bvp,
                                                 float* __restrict__ qf,
                                                 _Float16* __restrict__ kfh,
                                                 _Float16* __restrict__ vfh) {
  int tid = threadIdx.x;
  int m  = blockIdx.x / 128;
  int rb = blockIdx.x % 128;
  int wave = tid >> 6, lane = tid & 63, quad = lane >> 4, l16 = lane & 15;
  const float* bb = (m == 0) ? bqp : ((m == 1) ? bkp : bvp);
  int row0 = rb * 128 + wave * 32;

  h8 Ah[2][8], Al[2][8];
#pragma unroll
  for (int rt = 0; rt < 2; rt++)
#pragma unroll
    for (int kc = 0; kc < 8; kc++) {
      size_t off = (size_t)(row0 + rt * 16 + l16) * C_ + kc * 32 + quad * 8;
      Ah[rt][kc] = *(const h8*)(xh + off);
      Al[rt][kc] = *(const h8*)(xl + off);
    }
  const _Float16* whm = wh + (size_t)m * 65536;
  const _Float16* wlm = wl + (size_t)m * 65536;

#pragma unroll 1
  for (int cp = 0; cp < 2; cp++) {
    f4 acc[2][8];
#pragma unroll
    for (int rt = 0; rt < 2; rt++)
#pragma unroll
      for (int ct = 0; ct < 8; ct++) acc[rt][ct] = f4{0.f, 0.f, 0.f, 0.f};
#pragma unroll
    for (int kc = 0; kc < 8; kc++) {
#pragma unroll
      for (int ct = 0; ct < 8; ct++) {
        int col = cp * 128 + ct * 16 + l16;
        h8 bh = *(const h8*)(whm + (size_t)col * 256 + kc * 32 + quad * 8);
        h8 bl = *(const h8*)(wlm + (size_t)col * 256 + kc * 32 + quad * 8);
#pragma unroll
        for (int rt = 0; rt < 2; rt++) {
          acc[rt][ct] = __builtin_amdgcn_mfma_f32_16x16x32_f16(Ah[rt][kc], bh, acc[rt][ct], 0, 0, 0);
          acc[rt][ct] = __builtin_amdgcn_mfma_f32_16x16x32_f16(Ah[rt][kc], bl, acc[rt][ct], 0, 0, 0);
          acc[rt][ct] = __builtin_amdgcn_mfma_f32_16x16x32_f16(Al[rt][kc], bh, acc[rt][ct], 0, 0, 0);
        }
      }
    }
#pragma unroll
    for (int rt = 0; rt < 2; rt++)
#pragma unroll
      for (int ct = 0; ct < 8; ct++) {
        int col = cp * 128 + ct * 16 + l16;
        float bias = bb[col];
#pragma unroll
        for (int i = 0; i < 4; i++) {
          int r = row0 + rt * 16 + quad * 4 + i;
          float v = acc[rt][ct][i] + bias;
          if (m == 0)      qf[(size_t)r * C_ + col] = v;
          else if (m == 1) kfh[(size_t)r * C_ + col] = (_Float16)v;
          else             vfh[(size_t)r * C_ + col] = (_Float16)v;
        }
      }
  }
}

// --- split-f16 MFMA distance GEMM + tau-gated survivor queue + dense drains
// Progress invariant: marked cells are +inf, tau is ALWAYS finite (<=1e37), so
// every passing cell is real+unmarked; each overflow iteration consumes >=
// min(passes,QD) cells per row -> <= ceil(32/QD)=4 iterations per chunk.
// block: 128 targets x 1024 srcs (32-chunks), 4 waves. grid 512 x 256.
__global__ __launch_bounds__(256, 2) void k_knn(const _Float16* __restrict__ xh,
                                                const _Float16* __restrict__ xl,
                                                const float* __restrict__ sq,
                                                double* __restrict__ pd) {
  __shared__ __align__(16) _Float16 Bh[16 * 528]; // 16 segs x (2 rows x 256 + 8 pad)
  __shared__ __align__(16) _Float16 Bl[16 * 528];
  __shared__ __align__(16) float sc[128 * 36];    // row-major d2, stride 36
  __shared__ __align__(16) double buf[128 * QD];  // per-row survivor queue
  __shared__ float tauS[128];
  __shared__ unsigned cntS[128];
  __shared__ float sqS[32];
  __shared__ int ovf;

  const float INF = __builtin_inff();
  int tid = threadIdx.x;
  int wave = tid >> 6, lane = tid & 63, quad = lane >> 4, l16 = lane & 15;
  int bid = blockIdx.x;
  int s4 = bid & 3, tile = (bid >> 2) & 31, b = bid >> 7;
  int bN = b * N_, n0 = tile * 128, src0g = s4 * 1024;

  if (tid < 128) { tauS[tid] = 1e37f; cntS[tid] = 0u; }
  if (tid == 0) ovf = 0;

  // A-frags: wave's 32 target rows, full K, hi+lo, resident
  h8 Ah[2][8], Al[2][8];
  int tb = bN + n0 + wave * 32;
#pragma unroll
  for (int rt = 0; rt < 2; rt++)
#pragma unroll
    for (int kc = 0; kc < 8; kc++) {
      size_t off = (size_t)(tb + rt * 16 + l16) * C_ + kc * 32 + quad * 8;
      Ah[rt][kc] = *(const h8*)(xh + off);
      Al[rt][kc] = *(const h8*)(xl + off);
    }
  float sqT[2][4];
#pragma unroll
  for (int rt = 0; rt < 2; rt++)
#pragma unroll
    for (int i = 0; i < 4; i++)
      sqT[rt][i] = sq[tb + rt * 16 + quad * 4 + i];

  double karr[16];
#pragma unroll
  for (int p = 0; p < 16; p++) karr[p] = 1e300;
  int rowo = tid & 127, half = tid >> 7;

  // prologue: stage chunk 0. seg = 2 src rows = 1KB; lane i -> bytes [16i,16i+16)
  {
    const _Float16* gh = xh + (size_t)(bN + src0g) * C_ + lane * 8;
    const _Float16* gl = xl + (size_t)(bN + src0g) * C_ + lane * 8;
#pragma unroll
    for (int k = 0; k < 4; k++) {
      int seg = wave * 4 + k;
      gl2lds16(gh + seg * 512, &Bh[seg * 528]);
      gl2lds16(gl + seg * 512, &Bl[seg * 528]);
    }
    if (tid < 32) sqS[tid] = sq[bN + src0g + tid];
  }

  int hb0 = ((l16 >> 1) * 528) + ((l16 & 1) * 256) + quad * 8;          // ct=0 row
  int hb1 = (((16 + l16) >> 1) * 528) + ((l16 & 1) * 256) + quad * 8;   // ct=1 row

#pragma unroll 1
  for (int ch = 0; ch < 32; ch++) {
    int src0 = src0g + ch * 32;
    __syncthreads();                       // staged B(ch) + sqS(ch) visible

    f4 acc[2][2];
#pragma unroll
    for (int rt = 0; rt < 2; rt++)
#pragma unroll
      for (int ct = 0; ct < 2; ct++) acc[rt][ct] = f4{0.f, 0.f, 0.f, 0.f};
#pragma unroll
    for (int kc = 0; kc < 8; kc++) {
      h8 bh0 = *(const h8*)(&Bh[hb0 + kc * 32]);
      h8 bh1 = *(const h8*)(&Bh[hb1 + kc * 32]);
      h8 bl0 = *(const h8*)(&Bl[hb0 + kc * 32]);
      h8 bl1 = *(const h8*)(&Bl[hb1 + kc * 32]);
#pragma unroll
      for (int rt = 0; rt < 2; rt++) {
        acc[rt][0] = __builtin_amdgcn_mfma_f32_16x16x32_f16(Ah[rt][kc], bh0, acc[rt][0], 0, 0, 0);
        acc[rt][0] = __builtin_amdgcn_mfma_f32_16x16x32_f16(Ah[rt][kc], bl0, acc[rt][0], 0, 0, 0);
        acc[rt][0] = __builtin_amdgcn_mfma_f32_16x16x32_f16(Al[rt][kc], bh0, acc[rt][0], 0, 0, 0);
        acc[rt][1] = __builtin_amdgcn_mfma_f32_16x16x32_f16(Ah[rt][kc], bh1, acc[rt][1], 0, 0, 0);
        acc[rt][1] = __builtin_amdgcn_mfma_f32_16x16x32_f16(Ah[rt][kc], bl1, acc[rt][1], 0, 0, 0);
        acc[rt][1] = __builtin_amdgcn_mfma_f32_16x16x32_f16(Al[rt][kc], bh1, acc[rt][1], 0, 0, 0);
      }
    }
    // d2 -> sc row-major (stride 36), self-masked with +inf
    float sqSr[2] = {sqS[l16], sqS[16 + l16]};
#pragma unroll
    for (int rt = 0; rt < 2; rt++)
#pragma unroll
      for (int ct = 0; ct < 2; ct++) {
        int c = ct * 16 + l16;
#pragma unroll
        for (int i = 0; i < 4; i++) {
          int r = wave * 32 + rt * 16 + quad * 4 + i;
          float d2 = sqT[rt][i] + sqSr[ct] - 2.0f * acc[rt][ct][i];
          if (n0 + r == src0 + c) d2 = INF;
          sc[r * 36 + c] = d2;
        }
      }
    __syncthreads();                       // sc ready; all B(ch) reads done

    if (ch < 31) {                         // async-stage chunk ch+1
      int srcn = src0 + 32;
      const _Float16* gh = xh + (size_t)(bN + srcn) * C_ + lane * 8;
      const _Float16* gl = xl + (size_t)(bN + srcn) * C_ + lane * 8;
#pragma unroll
      for (int k = 0; k < 4; k++) {
        int seg = wave * 4 + k;
        gl2lds16(gh + seg * 512, &Bh[seg * 528]);
        gl2lds16(gl + seg * 512, &Bl[seg * 528]);
      }
      if (tid < 32) sqS[tid] = sq[bN + srcn + tid];
    }

    // tau-gated scan with overflow-drain-rescan (uniform exit, bounded iters)
    float tau = tauS[rowo];
#pragma unroll 1
    for (int iter = 0; iter < 8; iter++) { // math bound: 4 (progress invariant)
#pragma unroll
      for (int k4 = 0; k4 < 4; k4++) {
        float4 d4 = *(const float4*)(&sc[rowo * 36 + half * 16 + k4 * 4]);
        float dvv[4];
        *(float4*)dvv = d4;
#pragma unroll
        for (int e = 0; e < 4; e++) {
          if (dvv[e] <= tau) {             // tau finite => only real unmarked pass
            unsigned pos = atomicAdd(&cntS[rowo], 1u);
            if (pos < (unsigned)QD) {
              int c = half * 16 + k4 * 4 + e;
              double key = (double)dvv[e];
              key = __longlong_as_double(__double_as_longlong(key) |
                                         (unsigned)(src0 + c));
              buf[rowo * QD + pos] = key;
              sc[rowo * 36 + c] = INF;     // consumed: never re-passes
            } else {
              ovf = 1;                     // dropped; rescan will retry
            }
          }
        }
      }
      __syncthreads();                     // pushes + ovf visible
      int need = ovf;                      // uniform read
      __syncthreads();                     // all read before reset
      if (!need) break;
      if (tid == 0) ovf = 0;
      if (tid < 128) {                     // dense drain: one row per owner
        unsigned c = cntS[tid]; if (c > (unsigned)QD) c = (unsigned)QD;
        for (unsigned j = 0; j < c; j++) {
          double key = buf[tid * QD + j];
          if (key < karr[15]) {
#pragma unroll
            for (int p = 15; p >= 1; p--)
              karr[p] = fmin(fmax(key, karr[p - 1]), karr[p]);
            karr[0] = fmin(karr[0], key);
          }
        }
        cntS[tid] = 0u;
        tauS[tid] = fminf((float)karr[15], 1e37f);  // ALWAYS finite
      }
      __syncthreads();                     // tau/cnt updates visible
      tau = tauS[rowo];
    }
  }

  // final drain of leftover survivors, then emit sorted lists
  if (tid < 128) {
    unsigned c = cntS[tid]; if (c > (unsigned)QD) c = (unsigned)QD;
    for (unsigned j = 0; j < c; j++) {
      double key = buf[tid * QD + j];
      if (key < karr[15]) {
#pragma unroll
        for (int p = 15; p >= 1; p--)
          karr[p] = fmin(fmax(key, karr[p - 1]), karr[p]);
        karr[0] = fmin(karr[0], key);
      }
    }
#pragma unroll
    for (int p = 0; p < 16; p++)
      pd[((size_t)bid * 128 + tid) * 16 + p] = karr[p];
  }
}

// --------------------- merge 4 partial sorted packed lists -> top-16 indices
__global__ __launch_bounds__(256) void k_kmerge(const double* __restrict__ pd,
                                                int* __restrict__ idxo) {
  int g = blockIdx.x * 256 + threadIdx.x;      // 0..16383
  int b = g >> 12, n = g & 4095;
  int tile = n >> 7, r = n & 127;
  size_t base[4]; int p[4]; double hd[4];
#pragma unroll
  for (int s = 0; s < 4; s++) {
    base[s] = (size_t)(((b * 32 + tile) * 4 + s) * 128 + r) * 16;
    p[s] = 0;
    hd[s] = pd[base[s]];
  }
#pragma unroll
  for (int k = 0; k < 16; k++) {
    int bs = 0; double bd = hd[0];
#pragma unroll
    for (int s = 1; s < 4; s++) if (hd[s] < bd) { bd = hd[s]; bs = s; }
    idxo[(size_t)g * 16 + k] = (int)(__double_as_longlong(bd) & 0xFFF);
    p[bs]++;
    hd[bs] = (p[bs] < 16) ? pd[base[bs] + p[bs]] : 1e301;
  }
}

// ------------------------------- gather + attention (wave/node), f16 k/v
__global__ __launch_bounds__(256) void k_attn(const float* __restrict__ qf,
                                              const _Float16* __restrict__ kf,
                                              const _Float16* __restrict__ vf,
                                              const int* __restrict__ idxv,
                                              float* __restrict__ out) {
  int wave = threadIdx.x >> 6, lane = threadIdx.x & 63;
  int g = blockIdx.x * 4 + wave;               // node 0..16383
  int bN = (g >> 12) << 12;
  float4 q4 = *(const float4*)(qf + (size_t)g * C_ + lane * 4);
  int my = idxv[(size_t)g * 16 + (lane & 15)];
  const float scale = 0.17677669529663687f;    // 1/sqrt(32)

  float s[16];
  h4 vv[16];
#pragma unroll
  for (int j = 0; j < 16; j++) {
    int nb = __shfl(my, j);
    size_t base = (size_t)(bN + nb) * C_ + lane * 4;
    h4 k4 = *(const h4*)(kf + base);
    vv[j] = *(const h4*)(vf + base);
    float p = (float)k4[0] * q4.x + (float)k4[1] * q4.y +
              (float)k4[2] * q4.z + (float)k4[3] * q4.w;
    p += __shfl_xor(p, 1); p += __shfl_xor(p, 2); p += __shfl_xor(p, 4);
    s[j] = p * scale;
  }
  float mx = s[0];
#pragma unroll
  for (int j = 1; j < 16; j++) mx = fmaxf(mx, s[j]);
  float den = 0.f;
#pragma unroll
  for (int j = 0; j < 16; j++) { s[j] = __expf(s[j] - mx); den += s[j]; }
  float inv = 1.0f / den;
  float4 o; o.x = 0.f; o.y = 0.f; o.z = 0.f; o.w = 0.f;
#pragma unroll
  for (int j = 0; j < 16; j++) {
    float w = s[j] * inv;
    o.x = fmaf(w, (float)vv[j][0], o.x); o.y = fmaf(w, (float)vv[j][1], o.y);
    o.z = fmaf(w, (float)vv[j][2], o.z); o.w = fmaf(w, (float)vv[j][3], o.w);
  }
  *(float4*)(out + (size_t)g * C_ + lane * 4) = o;
}

extern "C" void kernel_launch(void* const* d_in, const int* in_sizes, int n_in,
                              void* d_out, int out_size, void* d_ws, size_t ws_size,
                              hipStream_t stream) {
  const float* x  = (const float*)d_in[0];
  const float* Wq = (const float*)d_in[1];
  const float* bq = (const float*)d_in[2];
  const float* Wk = (const float*)d_in[3];
  const float* bk = (const float*)d_in[4];
  const float* Wv = (const float*)d_in[5];
  const float* bv = (const float*)d_in[6];
  float* out = (float*)d_out;

  char* ws = (char*)d_ws;
  float*     sqp  = (float*)(ws + 0);                //  64 KB
  _Float16*  xh   = (_Float16*)(ws + 65536);         //   8 MB
  _Float16*  xl   = (_Float16*)(ws + 8454144);       //   8 MB
  float*     qf   = (float*)(ws + 16842752);         //  16 MB
  _Float16*  kfh  = (_Float16*)(ws + 33619968);      //   8 MB
  _Float16*  vfh  = (_Float16*)(ws + 42008576);      //   8 MB
  double*    pd   = (double*)(ws + 50397184);        //   8 MB
  int*       idxb = (int*)  (ws + 58785792);         //   1 MB
  _Float16*  whf  = (_Float16*)(ws + 59834368);      // 384 KB
  _Float16*  wlf  = (_Float16*)(ws + 60227584);      // 384 KB (total ~58 MB)

  k_prep  <<<4096, 256, 0, stream>>>(x, sqp, xh, xl);
  k_wsplit<<<768,  256, 0, stream>>>(Wq, Wk, Wv, whf, wlf);
  k_proj  <<<384,  256, 0, stream>>>(xh, xl, whf, wlf, bq, bk, bv, qf, kfh, vfh);
  k_knn   <<<512,  256, 0, stream>>>(xh, xl, sqp, pd);
  k_kmerge<<<64,   256, 0, stream>>>(pd, idxb);
  k_attn  <<<4096, 256, 0, stream>>>(qf, kfh, vfh, idxb, out);
}